// Round 1
// baseline (1747.261 us; speedup 1.0000x reference)
//
#include <hip/hip_runtime.h>
#include <math.h>

#define VOCAB 32000
#define D_IN  256
#define D_H   32
#define B_SZ  16
#define S_LEN 512
#define NTOK  (B_SZ * S_LEN)   // 8192
#define VCHUNKS (VOCAB / 256)  // 125
#define C1_TOK 32
#define C2_TOK 128

__device__ __forceinline__ float sigf(float x) {
    return 1.0f / (1.0f + __expf(-x));
}

// overflow-safe tanh: e^{-2|x|} <= 1 always
__device__ __forceinline__ float tanhfast(float x) {
    float ax = fabsf(x);
    float e = __expf(-2.0f * ax);
    float r = (1.0f - e) / (1.0f + e);
    return copysignf(r, x);
}

__device__ __forceinline__ float dot4(float4 a, float4 b) {
    return a.x * b.x + a.y * b.y + a.z * b.z + a.w * b.w;
}

// ---------------------------------------------------------------------------
// Kernel A: G1[t][g] = emb[x_ids[t]] . W_ih1[g] + (b_ih1[g] + b_hh1[g])
// 4 tokens per block, 128 threads (one gate per thread).
// ---------------------------------------------------------------------------
__global__ __launch_bounds__(128) void k_embed_gates(
    const int* __restrict__ x_ids, const float* __restrict__ emb,
    const float* __restrict__ W_ih1, const float* __restrict__ b_ih1,
    const float* __restrict__ b_hh1, float* __restrict__ G1)
{
    __shared__ float4 xs[4][64];
    const int tid = threadIdx.x;
    const int t0  = blockIdx.x * 4;
    const int r0  = tid >> 6, j = tid & 63;
    #pragma unroll
    for (int rr = 0; rr < 2; ++rr) {
        int r = rr * 2 + r0;
        long id = x_ids[t0 + r];
        xs[r][j] = ((const float4*)(emb + id * (long)D_IN))[j];
    }
    __syncthreads();

    const int g = tid;
    const float4* wrow = (const float4*)(W_ih1 + (long)g * D_IN);
    const float bias = b_ih1[g] + b_hh1[g];
    float a0 = bias, a1 = bias, a2 = bias, a3 = bias;
    #pragma unroll 8
    for (int jj = 0; jj < 64; ++jj) {
        float4 w = wrow[jj];
        a0 += dot4(w, xs[0][jj]);
        a1 += dot4(w, xs[1][jj]);
        a2 += dot4(w, xs[2][jj]);
        a3 += dot4(w, xs[3][jj]);
    }
    G1[(long)(t0 + 0) * 128 + g] = a0;
    G1[(long)(t0 + 1) * 128 + g] = a1;
    G1[(long)(t0 + 2) * 128 + g] = a2;
    G1[(long)(t0 + 3) * 128 + g] = a3;
}

// ---------------------------------------------------------------------------
// Kernel B: sequential 2-layer LSTM. One block per batch element, 128 threads
// (one gate per thread). Recurrent weights live in VGPRs; h state in LDS.
// ---------------------------------------------------------------------------
__global__ __launch_bounds__(128) void k_lstm_seq(
    const float* __restrict__ G1,
    const float* __restrict__ W_hh1,
    const float* __restrict__ W_ih2, const float* __restrict__ W_hh2,
    const float* __restrict__ b_ih2, const float* __restrict__ b_hh2,
    float* __restrict__ h2all)
{
    __shared__ float h1s[32], h2s[32], act1[128], act2[128];
    const int g = threadIdx.x;
    const int b = blockIdx.x;

    float4 w1[8], wi2[8], wh2[8];
    #pragma unroll
    for (int j = 0; j < 8; ++j) {
        w1[j]  = ((const float4*)(W_hh1 + (long)g * D_H))[j];
        wi2[j] = ((const float4*)(W_ih2 + (long)g * D_H))[j];
        wh2[j] = ((const float4*)(W_hh2 + (long)g * D_H))[j];
    }
    const float bias2 = b_ih2[g] + b_hh2[g];
    float c1 = 0.0f, c2 = 0.0f;
    if (g < 32) { h1s[g] = 0.0f; h2s[g] = 0.0f; }
    __syncthreads();

    const float* g1p = G1 + (long)b * S_LEN * 128 + g;
    float g1v = g1p[0];
    for (int s = 0; s < S_LEN; ++s) {
        float g1n = (s + 1 < S_LEN) ? g1p[(s + 1) * 128] : 0.0f;

        // cell-1 gate: G1 + h1 . W_hh1[g]
        float accA = g1v, accB = 0.0f;
        #pragma unroll
        for (int j = 0; j < 8; j += 2) {
            accA += dot4(w1[j],     ((const float4*)h1s)[j]);
            accB += dot4(w1[j + 1], ((const float4*)h1s)[j + 1]);
        }
        float acc = accA + accB;
        act1[g] = (g >= 64 && g < 96) ? tanhfast(acc) : sigf(acc);
        __syncthreads();

        if (g < 32) {
            float i = act1[g], f = act1[32 + g], gg = act1[64 + g], o = act1[96 + g];
            c1 = f * c1 + i * gg;
            h1s[g] = o * tanhfast(c1);
        }
        __syncthreads();

        // cell-2 gate: bias2 + h1 . W_ih2[g] + h2 . W_hh2[g]
        float a2A = bias2, a2B = 0.0f;
        #pragma unroll
        for (int j = 0; j < 8; j += 2) {
            a2A += dot4(wi2[j],     ((const float4*)h1s)[j]);
            a2B += dot4(wi2[j + 1], ((const float4*)h1s)[j + 1]);
            a2A += dot4(wh2[j],     ((const float4*)h2s)[j]);
            a2B += dot4(wh2[j + 1], ((const float4*)h2s)[j + 1]);
        }
        float acc2 = a2A + a2B;
        act2[g] = (g >= 64 && g < 96) ? tanhfast(acc2) : sigf(acc2);
        __syncthreads();

        if (g < 32) {
            float i = act2[g], f = act2[32 + g], gg = act2[64 + g], o = act2[96 + g];
            c2 = f * c2 + i * gg;
            float h2v = o * tanhfast(c2);
            h2s[g] = h2v;
            h2all[((long)b * S_LEN + s) * D_H + g] = h2v;
        }
        __syncthreads();
        g1v = g1n;
    }
}

// ---------------------------------------------------------------------------
// Kernel C1: per-token softmax denominator. One block covers C1_TOK tokens and
// the FULL vocab (thread strides vocab in 256-row chunks) -> no cross-block
// reduction. inv_sum[t] = 1 / sum_v exp(h2[t].W_fc[v] + b_fc[v]).
// ---------------------------------------------------------------------------
__global__ __launch_bounds__(256) void k_softmax_sum(
    const float* __restrict__ h2all, const float* __restrict__ W_fc,
    const float* __restrict__ b_fc, float* __restrict__ inv_sum)
{
    const int tid = threadIdx.x;
    const long t0 = (long)blockIdx.x * C1_TOK;

    float acc[C1_TOK];
    #pragma unroll
    for (int t = 0; t < C1_TOK; ++t) acc[t] = 0.0f;

    for (int c = 0; c < VCHUNKS; ++c) {
        const int v = c * 256 + tid;
        const float4* wr = (const float4*)(W_fc + (long)v * D_H);
        float4 w0 = wr[0], w1 = wr[1], w2 = wr[2], w3 = wr[3];
        float4 w4 = wr[4], w5 = wr[5], w6 = wr[6], w7 = wr[7];
        const float bb = b_fc[v];
        #pragma unroll
        for (int t = 0; t < C1_TOK; ++t) {
            const float4* hp = (const float4*)(h2all + (t0 + t) * D_H);
            float lA = bb, lB = 0.0f;
            lA += dot4(w0, hp[0]); lB += dot4(w1, hp[1]);
            lA += dot4(w2, hp[2]); lB += dot4(w3, hp[3]);
            lA += dot4(w4, hp[4]); lB += dot4(w5, hp[5]);
            lA += dot4(w6, hp[6]); lB += dot4(w7, hp[7]);
            acc[t] += __expf(lA + lB);
        }
    }

    __shared__ float red[C1_TOK][4];
    const int lane = tid & 63, wid = tid >> 6;
    #pragma unroll
    for (int t = 0; t < C1_TOK; ++t) {
        float v = acc[t];
        for (int off = 32; off; off >>= 1) v += __shfl_xor(v, off, 64);
        if (lane == 0) red[t][wid] = v;
    }
    __syncthreads();
    if (tid < C1_TOK) {
        float s = red[tid][0] + red[tid][1] + red[tid][2] + red[tid][3];
        inv_sum[t0 + tid] = 1.0f / s;
    }
}

// ---------------------------------------------------------------------------
// Kernel C2: recompute logits and write normalized softmax outputs.
// Thread owns one vocab row (W in VGPRs), loops over C2_TOK tokens.
// ---------------------------------------------------------------------------
__global__ __launch_bounds__(256) void k_softmax_out(
    const float* __restrict__ h2all, const float* __restrict__ W_fc,
    const float* __restrict__ b_fc, const float* __restrict__ inv_sum,
    float* __restrict__ out)
{
    const int tid = threadIdx.x;
    const int vc  = blockIdx.x % VCHUNKS;
    const long tc = blockIdx.x / VCHUNKS;
    const int v   = vc * 256 + tid;
    const long t0 = tc * C2_TOK;

    const float4* wr = (const float4*)(W_fc + (long)v * D_H);
    float4 w0 = wr[0], w1 = wr[1], w2 = wr[2], w3 = wr[3];
    float4 w4 = wr[4], w5 = wr[5], w6 = wr[6], w7 = wr[7];
    const float bb = b_fc[v];

    #pragma unroll 4
    for (int t = 0; t < C2_TOK; ++t) {
        const long tok = t0 + t;
        const float4* hp = (const float4*)(h2all + tok * D_H);
        float lA = bb, lB = 0.0f;
        lA += dot4(w0, hp[0]); lB += dot4(w1, hp[1]);
        lA += dot4(w2, hp[2]); lB += dot4(w3, hp[3]);
        lA += dot4(w4, hp[4]); lB += dot4(w5, hp[5]);
        lA += dot4(w6, hp[6]); lB += dot4(w7, hp[7]);
        out[tok * VOCAB + v] = __expf(lA + lB) * inv_sum[tok];
    }
}

// ---------------------------------------------------------------------------
extern "C" void kernel_launch(void* const* d_in, const int* in_sizes, int n_in,
                              void* d_out, int out_size, void* d_ws, size_t ws_size,
                              hipStream_t stream)
{
    const int*   x_ids = (const int*)d_in[0];
    const float* emb   = (const float*)d_in[1];
    const float* W_ih1 = (const float*)d_in[2];
    const float* W_hh1 = (const float*)d_in[3];
    const float* b_ih1 = (const float*)d_in[4];
    const float* b_hh1 = (const float*)d_in[5];
    const float* W_ih2 = (const float*)d_in[6];
    const float* W_hh2 = (const float*)d_in[7];
    const float* b_ih2 = (const float*)d_in[8];
    const float* b_hh2 = (const float*)d_in[9];
    const float* W_fc  = (const float*)d_in[10];
    const float* b_fc  = (const float*)d_in[11];
    float* out = (float*)d_out;

    float* G1      = (float*)d_ws;                 // NTOK*128 floats (4 MB)
    float* h2all   = G1 + (long)NTOK * 128;        // NTOK*32 floats (1 MB)
    float* inv_sum = h2all + (long)NTOK * D_H;     // NTOK floats

    k_embed_gates<<<NTOK / 4, 128, 0, stream>>>(x_ids, emb, W_ih1, b_ih1, b_hh1, G1);
    k_lstm_seq<<<B_SZ, 128, 0, stream>>>(G1, W_hh1, W_ih2, W_hh2, b_ih2, b_hh2, h2all);
    k_softmax_sum<<<NTOK / C1_TOK, 256, 0, stream>>>(h2all, W_fc, b_fc, inv_sum);
    k_softmax_out<<<VCHUNKS * (NTOK / C2_TOK), 256, 0, stream>>>(h2all, W_fc, b_fc, inv_sum, out);
}

// Round 3
// 936.480 us; speedup vs baseline: 1.8658x; 1.8658x over previous
//
#include <hip/hip_runtime.h>
#include <math.h>

#define VOCAB 32000
#define D_IN  256
#define D_H   32
#define B_SZ  16
#define S_LEN 512
#define NTOK  (B_SZ * S_LEN)   // 8192
#define NV1   16               // vocab splits in sum pass
#define VT1   (VOCAB / 16 / NV1)   // 125 tiles of 16 rows
#define NV2   25               // vocab splits in out pass
#define VT2   (VOCAB / 16 / NV2)   // 80 tiles

typedef __bf16 bf16;
typedef __attribute__((ext_vector_type(8))) __bf16 bf16x8;
typedef __attribute__((ext_vector_type(4))) float f32x4;

__device__ __forceinline__ float sigf(float x) {
    return 1.0f / (1.0f + __expf(-x));
}

__device__ __forceinline__ float tanhfast(float x) {
    float ax = fabsf(x);
    float e = __expf(-2.0f * ax);
    float r = (1.0f - e) / (1.0f + e);
    return copysignf(r, x);
}

__device__ __forceinline__ float dot4(float4 a, float4 b) {
    return a.x * b.x + a.y * b.y + a.z * b.z + a.w * b.w;
}

// ---------------------------------------------------------------------------
// Convert W_fc (f32 [32000][32]) to bf16 hi/lo split arrays.
// ---------------------------------------------------------------------------
__global__ __launch_bounds__(256) void k_cvt_w(
    const float* __restrict__ W, bf16* __restrict__ Whi, bf16* __restrict__ Wlo)
{
    const long i = ((long)blockIdx.x * 256 + threadIdx.x) * 4;
    float4 w = *(const float4*)(W + i);
    bf16 h0 = (bf16)w.x, h1 = (bf16)w.y, h2 = (bf16)w.z, h3 = (bf16)w.w;
    bf16 l0 = (bf16)(w.x - (float)h0), l1 = (bf16)(w.y - (float)h1);
    bf16 l2 = (bf16)(w.z - (float)h2), l3 = (bf16)(w.w - (float)h3);
    typedef __attribute__((ext_vector_type(4))) __bf16 bf16x4;
    bf16x4 hv = {h0, h1, h2, h3}, lv = {l0, l1, l2, l3};
    *(bf16x4*)(Whi + i) = hv;
    *(bf16x4*)(Wlo + i) = lv;
}

// ---------------------------------------------------------------------------
// Kernel A: G1[t][g] = emb[x_ids[t]] . W_ih1[g] + (b_ih1[g] + b_hh1[g])
// ---------------------------------------------------------------------------
__global__ __launch_bounds__(128) void k_embed_gates(
    const int* __restrict__ x_ids, const float* __restrict__ emb,
    const float* __restrict__ W_ih1, const float* __restrict__ b_ih1,
    const float* __restrict__ b_hh1, float* __restrict__ G1)
{
    __shared__ float4 xs[4][64];
    const int tid = threadIdx.x;
    const int t0  = blockIdx.x * 4;
    const int r0  = tid >> 6, j = tid & 63;
    #pragma unroll
    for (int rr = 0; rr < 2; ++rr) {
        int r = rr * 2 + r0;
        long id = x_ids[t0 + r];
        xs[r][j] = ((const float4*)(emb + id * (long)D_IN))[j];
    }
    __syncthreads();

    const int g = tid;
    const float4* wrow = (const float4*)(W_ih1 + (long)g * D_IN);
    const float bias = b_ih1[g] + b_hh1[g];
    float a0 = bias, a1 = bias, a2 = bias, a3 = bias;
    #pragma unroll 8
    for (int jj = 0; jj < 64; ++jj) {
        float4 w = wrow[jj];
        a0 += dot4(w, xs[0][jj]);
        a1 += dot4(w, xs[1][jj]);
        a2 += dot4(w, xs[2][jj]);
        a3 += dot4(w, xs[3][jj]);
    }
    G1[(long)(t0 + 0) * 128 + g] = a0;
    G1[(long)(t0 + 1) * 128 + g] = a1;
    G1[(long)(t0 + 2) * 128 + g] = a2;
    G1[(long)(t0 + 3) * 128 + g] = a3;
}

// ---------------------------------------------------------------------------
// Kernel B: sequential 2-layer LSTM. Writes h2 as bf16 hi/lo split.
// ---------------------------------------------------------------------------
__global__ __launch_bounds__(128) void k_lstm_seq(
    const float* __restrict__ G1,
    const float* __restrict__ W_hh1,
    const float* __restrict__ W_ih2, const float* __restrict__ W_hh2,
    const float* __restrict__ b_ih2, const float* __restrict__ b_hh2,
    bf16* __restrict__ Hhi, bf16* __restrict__ Hlo)
{
    __shared__ float h1s[32], h2s[32], act1[128], act2[128];
    const int g = threadIdx.x;
    const int b = blockIdx.x;

    float4 w1[8], wi2[8], wh2[8];
    #pragma unroll
    for (int j = 0; j < 8; ++j) {
        w1[j]  = ((const float4*)(W_hh1 + (long)g * D_H))[j];
        wi2[j] = ((const float4*)(W_ih2 + (long)g * D_H))[j];
        wh2[j] = ((const float4*)(W_hh2 + (long)g * D_H))[j];
    }
    const float bias2 = b_ih2[g] + b_hh2[g];
    float c1 = 0.0f, c2 = 0.0f;
    if (g < 32) { h1s[g] = 0.0f; h2s[g] = 0.0f; }
    __syncthreads();

    const float* g1p = G1 + (long)b * S_LEN * 128 + g;
    float g1v = g1p[0];
    for (int s = 0; s < S_LEN; ++s) {
        float g1n = (s + 1 < S_LEN) ? g1p[(s + 1) * 128] : 0.0f;

        float accA = g1v, accB = 0.0f;
        #pragma unroll
        for (int j = 0; j < 8; j += 2) {
            accA += dot4(w1[j],     ((const float4*)h1s)[j]);
            accB += dot4(w1[j + 1], ((const float4*)h1s)[j + 1]);
        }
        float acc = accA + accB;
        act1[g] = (g >= 64 && g < 96) ? tanhfast(acc) : sigf(acc);
        __syncthreads();

        if (g < 32) {
            float i = act1[g], f = act1[32 + g], gg = act1[64 + g], o = act1[96 + g];
            c1 = f * c1 + i * gg;
            h1s[g] = o * tanhfast(c1);
        }
        __syncthreads();

        float a2A = bias2, a2B = 0.0f;
        #pragma unroll
        for (int j = 0; j < 8; j += 2) {
            a2A += dot4(wi2[j],     ((const float4*)h1s)[j]);
            a2B += dot4(wi2[j + 1], ((const float4*)h1s)[j + 1]);
            a2A += dot4(wh2[j],     ((const float4*)h2s)[j]);
            a2B += dot4(wh2[j + 1], ((const float4*)h2s)[j + 1]);
        }
        float acc2 = a2A + a2B;
        act2[g] = (g >= 64 && g < 96) ? tanhfast(acc2) : sigf(acc2);
        __syncthreads();

        if (g < 32) {
            float i = act2[g], f = act2[32 + g], gg = act2[64 + g], o = act2[96 + g];
            c2 = f * c2 + i * gg;
            float h2v = o * tanhfast(c2);
            h2s[g] = h2v;
            long idx = ((long)b * S_LEN + s) * D_H + g;
            bf16 hi = (bf16)h2v;
            Hhi[idx] = hi;
            Hlo[idx] = (bf16)(h2v - (float)hi);
        }
        __syncthreads();
        g1v = g1n;
    }
}

// ---------------------------------------------------------------------------
// Kernel C1 (MFMA): partial softmax denominators.
// Block = 4 waves; wave owns 32 tokens (2 A-tiles), scans a vocab chunk.
// logits = Ahi.Bhi + Alo.Bhi + Ahi.Blo  (f32 accum).
// ---------------------------------------------------------------------------
__global__ __launch_bounds__(256) void k_fc_sum(
    const bf16* __restrict__ Hhi, const bf16* __restrict__ Hlo,
    const bf16* __restrict__ Whi, const bf16* __restrict__ Wlo,
    const float* __restrict__ b_fc, float* __restrict__ partial)
{
    const int lane = threadIdx.x & 63;
    const int wid  = threadIdx.x >> 6;
    const int tg   = blockIdx.x / NV1;
    const int nv   = blockIdx.x % NV1;
    const int t0   = tg * 128 + wid * 32;
    const int lr   = lane & 15, lq = lane >> 4;

    const long arow0 = (long)(t0 + lr) * D_H + lq * 8;
    const long arow1 = arow0 + 16 * D_H;
    bf16x8 a0h = *(const bf16x8*)(Hhi + arow0);
    bf16x8 a0l = *(const bf16x8*)(Hlo + arow0);
    bf16x8 a1h = *(const bf16x8*)(Hhi + arow1);
    bf16x8 a1l = *(const bf16x8*)(Hlo + arow1);

    f32x4 acc0 = {0.f, 0.f, 0.f, 0.f}, acc1 = {0.f, 0.f, 0.f, 0.f};
    const f32x4 z = {0.f, 0.f, 0.f, 0.f};
    int v0 = nv * (VOCAB / NV1);
    for (int tile = 0; tile < VT1; ++tile, v0 += 16) {
        const long brow = (long)(v0 + lr) * D_H + lq * 8;
        bf16x8 bh = *(const bf16x8*)(Whi + brow);
        bf16x8 bl = *(const bf16x8*)(Wlo + brow);
        float bias = b_fc[v0 + lr];
        f32x4 d0 = __builtin_amdgcn_mfma_f32_16x16x32_bf16(a0h, bh, z, 0, 0, 0);
        d0 = __builtin_amdgcn_mfma_f32_16x16x32_bf16(a0l, bh, d0, 0, 0, 0);
        d0 = __builtin_amdgcn_mfma_f32_16x16x32_bf16(a0h, bl, d0, 0, 0, 0);
        f32x4 d1 = __builtin_amdgcn_mfma_f32_16x16x32_bf16(a1h, bh, z, 0, 0, 0);
        d1 = __builtin_amdgcn_mfma_f32_16x16x32_bf16(a1l, bh, d1, 0, 0, 0);
        d1 = __builtin_amdgcn_mfma_f32_16x16x32_bf16(a1h, bl, d1, 0, 0, 0);
        #pragma unroll
        for (int r = 0; r < 4; ++r) {
            acc0[r] += __expf(d0[r] + bias);
            acc1[r] += __expf(d1[r] + bias);
        }
    }

    // reduce over the 16 vocab-lanes of each group
    #pragma unroll
    for (int m = 1; m < 16; m <<= 1) {
        #pragma unroll
        for (int r = 0; r < 4; ++r) {
            acc0[r] += __shfl_xor(acc0[r], m, 64);
            acc1[r] += __shfl_xor(acc1[r], m, 64);
        }
    }
    if (lr == 0) {
        #pragma unroll
        for (int r = 0; r < 4; ++r) {
            partial[(long)nv * NTOK + t0 + lq * 4 + r]      = acc0[r];
            partial[(long)nv * NTOK + t0 + 16 + lq * 4 + r] = acc1[r];
        }
    }
}

__global__ __launch_bounds__(256) void k_inv(
    const float* __restrict__ partial, float* __restrict__ inv_sum)
{
    const int t = blockIdx.x * 256 + threadIdx.x;
    float s = 0.0f;
    #pragma unroll
    for (int nv = 0; nv < NV1; ++nv) s += partial[(long)nv * NTOK + t];
    inv_sum[t] = 1.0f / s;
}

// ---------------------------------------------------------------------------
// Kernel C2 (MFMA): recompute logits, write normalized softmax.
// ---------------------------------------------------------------------------
__global__ __launch_bounds__(256) void k_fc_out(
    const bf16* __restrict__ Hhi, const bf16* __restrict__ Hlo,
    const bf16* __restrict__ Whi, const bf16* __restrict__ Wlo,
    const float* __restrict__ b_fc, const float* __restrict__ inv_sum,
    float* __restrict__ out)
{
    const int lane = threadIdx.x & 63;
    const int wid  = threadIdx.x >> 6;
    const int tg   = blockIdx.x / NV2;
    const int nv   = blockIdx.x % NV2;
    const int t0   = tg * 128 + wid * 32;
    const int lr   = lane & 15, lq = lane >> 4;

    const long arow0 = (long)(t0 + lr) * D_H + lq * 8;
    const long arow1 = arow0 + 16 * D_H;
    bf16x8 a0h = *(const bf16x8*)(Hhi + arow0);
    bf16x8 a0l = *(const bf16x8*)(Hlo + arow0);
    bf16x8 a1h = *(const bf16x8*)(Hhi + arow1);
    bf16x8 a1l = *(const bf16x8*)(Hlo + arow1);

    float inv0[4], inv1[4];
    #pragma unroll
    for (int r = 0; r < 4; ++r) {
        inv0[r] = inv_sum[t0 + lq * 4 + r];
        inv1[r] = inv_sum[t0 + 16 + lq * 4 + r];
    }

    const f32x4 z = {0.f, 0.f, 0.f, 0.f};
    int v0 = nv * (VOCAB / NV2);
    for (int tile = 0; tile < VT2; ++tile, v0 += 16) {
        const long brow = (long)(v0 + lr) * D_H + lq * 8;
        bf16x8 bh = *(const bf16x8*)(Whi + brow);
        bf16x8 bl = *(const bf16x8*)(Wlo + brow);
        float bias = b_fc[v0 + lr];
        f32x4 d0 = __builtin_amdgcn_mfma_f32_16x16x32_bf16(a0h, bh, z, 0, 0, 0);
        d0 = __builtin_amdgcn_mfma_f32_16x16x32_bf16(a0l, bh, d0, 0, 0, 0);
        d0 = __builtin_amdgcn_mfma_f32_16x16x32_bf16(a0h, bl, d0, 0, 0, 0);
        f32x4 d1 = __builtin_amdgcn_mfma_f32_16x16x32_bf16(a1h, bh, z, 0, 0, 0);
        d1 = __builtin_amdgcn_mfma_f32_16x16x32_bf16(a1l, bh, d1, 0, 0, 0);
        d1 = __builtin_amdgcn_mfma_f32_16x16x32_bf16(a1h, bl, d1, 0, 0, 0);
        const int vcol = v0 + lr;
        #pragma unroll
        for (int r = 0; r < 4; ++r) {
            out[(long)(t0 + lq * 4 + r) * VOCAB + vcol] =
                __expf(d0[r] + bias) * inv0[r];
            out[(long)(t0 + 16 + lq * 4 + r) * VOCAB + vcol] =
                __expf(d1[r] + bias) * inv1[r];
        }
    }
}

// ---------------------------------------------------------------------------
extern "C" void kernel_launch(void* const* d_in, const int* in_sizes, int n_in,
                              void* d_out, int out_size, void* d_ws, size_t ws_size,
                              hipStream_t stream)
{
    const int*   x_ids = (const int*)d_in[0];
    const float* emb   = (const float*)d_in[1];
    const float* W_ih1 = (const float*)d_in[2];
    const float* W_hh1 = (const float*)d_in[3];
    const float* b_ih1 = (const float*)d_in[4];
    const float* b_hh1 = (const float*)d_in[5];
    const float* W_ih2 = (const float*)d_in[6];
    const float* W_hh2 = (const float*)d_in[7];
    const float* b_ih2 = (const float*)d_in[8];
    const float* b_hh2 = (const float*)d_in[9];
    const float* W_fc  = (const float*)d_in[10];
    const float* b_fc  = (const float*)d_in[11];
    float* out = (float*)d_out;

    // workspace layout (bytes): keep 16B alignment everywhere
    char* p = (char*)d_ws;
    float* G1      = (float*)p;            p += (long)NTOK * 128 * 4;   // 4 MB
    bf16* Hhi      = (bf16*)p;             p += (long)NTOK * D_H * 2;   // 512 KB
    bf16* Hlo      = (bf16*)p;             p += (long)NTOK * D_H * 2;   // 512 KB
    bf16* Whi      = (bf16*)p;             p += (long)VOCAB * D_H * 2;  // 2 MB
    bf16* Wlo      = (bf16*)p;             p += (long)VOCAB * D_H * 2;  // 2 MB
    float* partial = (float*)p;            p += (long)NV1 * NTOK * 4;   // 512 KB
    float* inv_sum = (float*)p;            p += (long)NTOK * 4;         // 32 KB

    k_cvt_w<<<VOCAB * D_H / (256 * 4), 256, 0, stream>>>(W_fc, Whi, Wlo);
    k_embed_gates<<<NTOK / 4, 128, 0, stream>>>(x_ids, emb, W_ih1, b_ih1, b_hh1, G1);
    k_lstm_seq<<<B_SZ, 128, 0, stream>>>(G1, W_hh1, W_ih2, W_hh2, b_ih2, b_hh2, Hhi, Hlo);
    k_fc_sum<<<(NTOK / 128) * NV1, 256, 0, stream>>>(Hhi, Hlo, Whi, Wlo, b_fc, partial);
    k_inv<<<NTOK / 256, 256, 0, stream>>>(partial, inv_sum);
    k_fc_out<<<(NTOK / 128) * NV2, 256, 0, stream>>>(Hhi, Hlo, Whi, Wlo, b_fc, inv_sum, out);
}